// Round 1
// baseline (6477.648 us; speedup 1.0000x reference)
//
#include <hip/hip_runtime.h>
#include <math.h>

#define NCH 64       // C
#define T_LEN 65536
#define TT 64        // time tile per block
#define NLAYER 18

// ---------------------------------------------------------------------------
// Input 1x1 conv: out[b,c,t] = in_w[c]*x[b,t] + in_b[c]
// gid enumerates (b*C + c)*T + t, so writes are fully coalesced.
// ---------------------------------------------------------------------------
__global__ void input_conv_kernel(const float* __restrict__ x,
                                  const float* __restrict__ in_w,
                                  const float* __restrict__ in_b,
                                  float* __restrict__ out) {
    int gid = blockIdx.x * 256 + threadIdx.x;     // over B*C*T = 16M
    int t  = gid & (T_LEN - 1);
    int bc = gid >> 16;                           // b*64 + c
    int c  = bc & 63;
    int b  = bc >> 6;
    out[gid] = in_w[c] * x[(b << 16) | t] + in_b[c];
}

// ---------------------------------------------------------------------------
// One gated residual layer.
//   h[o,t]   = sum_c hw[o,c,0]*prev[c,t-d] + hw[o,c,1]*prev[c,t] + hb[o]
//   gated    = tanh(h[0:64]) * sigmoid(h[64:128])
//   next[o]  = sum_c rw[o,c]*gated[c] + rb[o] + prev[o,t]
//   acc[b,t] += sum_c mw[c]*gated[c]          (skip->mix fused, no skip tensor)
//
// Block: 256 threads = 4 waves. Wave g computes rows o' = g*16+r (both tanh
// row o' and sigmoid row o'+64 -> gating is thread-local). Time tile TT=64,
// lane = tt -> all LDS accesses are stride-1 in tt (2-way aliasing only,
// free on gfx950). Weight addresses made wave-uniform via readfirstlane so
// the compiler emits scalar loads (one fetch broadcast to 64 lanes).
// ---------------------------------------------------------------------------
__global__ __launch_bounds__(256) void layer_kernel(
    const float* __restrict__ prev,   // [B][C][T]
    float* __restrict__ next,         // [B][C][T]
    float* __restrict__ acc,          // [B][T]
    const float* __restrict__ hw,     // this layer: [128][64][2]
    const float* __restrict__ hb,     // [128]
    const float* __restrict__ rw,     // [64][64]
    const float* __restrict__ rb,     // [64]
    const float* __restrict__ mw,     // [64] (this layer's mix slice)
    int d) {
    __shared__ float cur [NCH][TT];
    __shared__ float past[NCH][TT];
    __shared__ float gsh [NCH][TT];

    int tile = blockIdx.x;            // b*(T/TT) + tile index
    int b    = tile >> 10;            // T/TT = 1024
    int t0   = (tile & 1023) << 6;

    const float* pb = prev + (size_t)b * NCH * T_LEN;

    // ---- stage prev[:, t0..t0+63] and prev[:, t0-d..t0-d+63] into LDS ----
    for (int idx = threadIdx.x; idx < NCH * TT; idx += 256) {
        int c  = idx >> 6;
        int tt = idx & 63;
        int t  = t0 + tt;
        cur[c][tt] = pb[c * T_LEN + t];
        int tp = t - d;
        past[c][tt] = (tp >= 0) ? pb[c * T_LEN + tp] : 0.0f;
    }
    __syncthreads();

    int tt = threadIdx.x & 63;
    int g  = __builtin_amdgcn_readfirstlane((int)(threadIdx.x >> 6)); // 0..3
    int obase = g * 16;

    // ---- hid conv (paired tanh/sigmoid rows) ----
    float accT[16], accS[16];
#pragma unroll
    for (int r = 0; r < 16; ++r) {
        accT[r] = hb[obase + r];
        accS[r] = hb[obase + r + 64];
    }
    for (int c8 = 0; c8 < NCH; c8 += 8) {
        float cr[8], pr[8];
#pragma unroll
        for (int j = 0; j < 8; ++j) {
            cr[j] = cur [c8 + j][tt];
            pr[j] = past[c8 + j][tt];
        }
#pragma unroll
        for (int r = 0; r < 16; ++r) {
            const float* wT = hw + (obase + r) * 128 + c8 * 2;   // row o'
            const float* wS = wT + 64 * 128;                     // row o'+64
            float aT = accT[r], aS = accS[r];
#pragma unroll
            for (int j = 0; j < 8; ++j) {
                aT += wT[2 * j] * pr[j] + wT[2 * j + 1] * cr[j];
                aS += wS[2 * j] * pr[j] + wS[2 * j + 1] * cr[j];
            }
            accT[r] = aT;
            accS[r] = aS;
        }
    }

    // ---- gate: gated = tanh(hT) * sigmoid(hS) ----
#pragma unroll
    for (int r = 0; r < 16; ++r) {
        float s = 1.0f / (1.0f + expf(-accS[r]));
        gsh[obase + r][tt] = tanhf(accT[r]) * s;
    }
    __syncthreads();

    // ---- res 1x1 conv + residual add ----
    float racc[16];
#pragma unroll
    for (int r = 0; r < 16; ++r) racc[r] = rb[obase + r];
    for (int c8 = 0; c8 < NCH; c8 += 8) {
        float gr[8];
#pragma unroll
        for (int j = 0; j < 8; ++j) gr[j] = gsh[c8 + j][tt];
#pragma unroll
        for (int r = 0; r < 16; ++r) {
            const float* w = rw + (obase + r) * 64 + c8;
            float a = racc[r];
#pragma unroll
            for (int j = 0; j < 8; ++j) a += w[j] * gr[j];
            racc[r] = a;
        }
    }
    float* nb = next + (size_t)b * NCH * T_LEN;
#pragma unroll
    for (int r = 0; r < 16; ++r) {
        int o = obase + r;
        nb[o * T_LEN + t0 + tt] = racc[r] + cur[o][tt];
    }

    // ---- fused skip->mix accumulation (one thread per (b,t)) ----
    if (g == 0) {
        float s = 0.0f;
#pragma unroll
        for (int c = 0; c < NCH; ++c) s += mw[c] * gsh[c][tt];
        acc[(size_t)b * T_LEN + t0 + tt] += s;
    }
}

// ---------------------------------------------------------------------------
__global__ void finalize_kernel(const float* __restrict__ acc,
                                const float* __restrict__ mix_b,
                                float* __restrict__ out) {
    int gid = blockIdx.x * 256 + threadIdx.x;     // over B*T = 262144
    out[gid] = acc[gid] + mix_b[0];
}

// ---------------------------------------------------------------------------
extern "C" void kernel_launch(void* const* d_in, const int* in_sizes, int n_in,
                              void* d_out, int out_size, void* d_ws, size_t ws_size,
                              hipStream_t stream) {
    const float* x     = (const float*)d_in[0];
    const float* in_w  = (const float*)d_in[1];
    const float* in_b  = (const float*)d_in[2];
    const float* hid_w = (const float*)d_in[3];  // [18][128][64][2]
    const float* hid_b = (const float*)d_in[4];  // [18][128]
    const float* res_w = (const float*)d_in[5];  // [18][64][64]
    const float* res_b = (const float*)d_in[6];  // [18][64]
    const float* mix_w = (const float*)d_in[7];  // [1152]
    const float* mix_b = (const float*)d_in[8];  // [1]
    float* out = (float*)d_out;

    const size_t act_elems = 4ull * NCH * T_LEN;     // 16M floats = 64 MB
    float* bufA = (float*)d_ws;
    float* bufB = bufA + act_elems;
    float* acc  = bufB + act_elems;                  // [B][T] = 1 MB

    hipMemsetAsync(acc, 0, 4ull * T_LEN * sizeof(float), stream);

    // input conv: B*C*T / 256 = 65536 blocks
    input_conv_kernel<<<65536, 256, 0, stream>>>(x, in_w, in_b, bufA);

    static const int dil[NLAYER] = {1, 2, 4, 8, 16, 32, 64, 128, 256,
                                    1, 2, 4, 8, 16, 32, 64, 128, 256};
    const float* cur = bufA;
    float* nxt = bufB;
    for (int i = 0; i < NLAYER; ++i) {
        layer_kernel<<<4 * 1024, 256, 0, stream>>>(
            cur, nxt, acc,
            hid_w + (size_t)i * 128 * 64 * 2,
            hid_b + (size_t)i * 128,
            res_w + (size_t)i * 64 * 64,
            res_b + (size_t)i * 64,
            mix_w + (size_t)i * 64,
            dil[i]);
        const float* tmp = nxt;
        nxt = (float*)cur;
        cur = tmp;
    }

    finalize_kernel<<<1024, 256, 0, stream>>>(acc, mix_b, out);
}

// Round 3
// 762.562 us; speedup vs baseline: 8.4946x; 8.4946x over previous
//
#include <hip/hip_runtime.h>
#include <hip/hip_bf16.h>
#include <math.h>

#define NCH 64       // C
#define T_LEN 65536
#define NLAYER 18

typedef __attribute__((ext_vector_type(8))) short bf16x8;   // 8 bf16 = 4 VGPRs
typedef __attribute__((ext_vector_type(4))) short bf16x4;   // 4 bf16 = 2 VGPRs
typedef __attribute__((ext_vector_type(4))) float f32x4;

// ---------------------------------------------------------------------------
// Input 1x1 conv -> bf16 [B][T][C] layout (channel-innermost).
// Thread handles one (b,t,c8) group of 8 channels -> one 16B store.
// ---------------------------------------------------------------------------
__global__ void input_conv_kernel(const float* __restrict__ x,
                                  const float* __restrict__ in_w,
                                  const float* __restrict__ in_b,
                                  __hip_bfloat16* __restrict__ out) {
    int gid = blockIdx.x * 256 + threadIdx.x;     // over B*T*8 = 2M
    int c8 = gid & 7;
    int t  = (gid >> 3) & (T_LEN - 1);
    int b  = gid >> 19;
    float xv = x[(size_t)b * T_LEN + t];
    bf16x8 v;
#pragma unroll
    for (int j = 0; j < 8; ++j) {
        float o = in_w[c8 * 8 + j] * xv + in_b[c8 * 8 + j];
        __hip_bfloat16 h = __float2bfloat16(o);
        v[j] = *(short*)&h;
    }
    *(bf16x8*)(out + ((size_t)b * T_LEN + t) * NCH + c8 * 8) = v;
}

// ---------------------------------------------------------------------------
// Pre-convert weights to bf16 once per launch (ws is re-poisoned each call).
// whid[l][o][k]: k<64 -> hid_w[l][o][k][0] (past tap), k>=64 -> [k-64][1] (cur)
// ---------------------------------------------------------------------------
__global__ void convert_weights_kernel(const float* __restrict__ hid_w,
                                       const float* __restrict__ res_w,
                                       __hip_bfloat16* __restrict__ whid,
                                       __hip_bfloat16* __restrict__ wres) {
    int gid = blockIdx.x * 256 + threadIdx.x;
    if (gid < NLAYER * 128 * 128) {               // 294912 = 18<<14
        int l   = gid >> 14;
        int rem = gid & 16383;
        int o   = rem >> 7;
        int k   = rem & 127;
        float v = (k < 64)
            ? hid_w[((l * 128 + o) * 64 + k) * 2]
            : hid_w[((l * 128 + o) * 64 + (k - 64)) * 2 + 1];
        whid[gid] = __float2bfloat16(v);
    }
    if (gid < NLAYER * 64 * 64) {
        wres[gid] = __float2bfloat16(res_w[gid]);
    }
}

// ---------------------------------------------------------------------------
// One gated residual layer, MFMA, bf16 [B][T][C] activations.
// Block = 256 thr (4 waves) = one 64-timestep tile of one batch.
// GEMM1: H[128][64] = Whid[128][128k] @ X[128k][64t]; wave w owns row-tiles
// {16w (tanh), 64+16w (sigmoid)} so the gate pair is register-local.
// GEMM2: R[64][64] = Wres @ gated. Skip->mix fused into acc[b][t].
// LDS tiles [t][k] pitch 72 (144B rows: bank stride 4 -> 2-way max = free).
// ---------------------------------------------------------------------------
__global__ __launch_bounds__(256) void layer_mfma_kernel(
    const __hip_bfloat16* __restrict__ prev,   // [B][T][C] bf16
    __hip_bfloat16* __restrict__ next,         // [B][T][C] bf16
    float* __restrict__ acc,                   // [B][T] fp32 skip accumulator
    const __hip_bfloat16* __restrict__ whid,   // [128][128] this layer
    const float* __restrict__ hb,              // [128]
    const __hip_bfloat16* __restrict__ wres,   // [64][64]
    const float* __restrict__ rb,              // [64]
    const float* __restrict__ mw,              // [64] this layer's mix slice
    int d) {
    __shared__ __align__(16) __hip_bfloat16 Xp[64 * 72];  // past tap [t][c]
    __shared__ __align__(16) __hip_bfloat16 Xc[64 * 72];  // cur  tap [t][c]
    __shared__ __align__(16) __hip_bfloat16 Gt[64 * 72];  // gated    [t][c]
    __shared__ float skb[4 * 64];

    int tile = blockIdx.x;
    int b    = tile >> 10;                 // 1024 tiles per batch
    int t0   = (tile & 1023) << 6;
    const __hip_bfloat16* pb = prev + ((size_t)b * T_LEN + t0) * NCH;
    __hip_bfloat16*       nb = next + ((size_t)b * T_LEN + t0) * NCH;

    int tid = threadIdx.x;
    int rr  = tid >> 3;                    // 0..31 (t within half-tile)
    int co  = (tid & 7) * 8;               // channel group

    // ---- stage both taps: 16B coalesced loads, no transpose needed ----
#pragma unroll
    for (int pass = 0; pass < 2; ++pass) {
        int r = pass * 32 + rr;
        *(bf16x8*)(&Xc[r * 72 + co]) = *(const bf16x8*)(pb + r * NCH + co);
        int tp = t0 + r - d;
        bf16x8 pv = {0, 0, 0, 0, 0, 0, 0, 0};
        if (tp >= 0)
            pv = *(const bf16x8*)(prev + ((size_t)b * T_LEN + tp) * NCH + co);
        *(bf16x8*)(&Xp[r * 72 + co]) = pv;
    }
    __syncthreads();

    int lane = tid & 63;
    int w4   = tid >> 6;                   // wave id 0..3
    int l15  = lane & 15;
    int quad = lane >> 4;
    int m0   = w4 * 16;

    // ---- GEMM1: K-loop over 128 stacked channels (64 past + 64 cur) ----
    f32x4 zz = {0.f, 0.f, 0.f, 0.f};
    f32x4 accT[4], accS[4];
#pragma unroll
    for (int nt = 0; nt < 4; ++nt) { accT[nt] = zz; accS[nt] = zz; }

    const __hip_bfloat16* whT = whid + (size_t)(m0 + l15) * 128;
    const __hip_bfloat16* whS = whid + (size_t)(64 + m0 + l15) * 128;

#pragma unroll
    for (int k0 = 0; k0 < 128; k0 += 32) {
        bf16x8 aT = *(const bf16x8*)(whT + k0 + quad * 8);
        bf16x8 aS = *(const bf16x8*)(whS + k0 + quad * 8);
        const __hip_bfloat16* src = (k0 < 64) ? Xp : Xc;
        int kk = (k0 & 63) + quad * 8;
#pragma unroll
        for (int nt = 0; nt < 4; ++nt) {
            bf16x8 bx = *(const bf16x8*)(&src[(nt * 16 + l15) * 72 + kk]);
            accT[nt] = __builtin_amdgcn_mfma_f32_16x16x32_bf16(aT, bx, accT[nt], 0, 0, 0);
            accS[nt] = __builtin_amdgcn_mfma_f32_16x16x32_bf16(aS, bx, accS[nt], 0, 0, 0);
        }
    }

    // ---- gate: tanh(hT)*sigmoid(hS) -> Gt[t][c] bf16 ----
    float hbT[4], hbS[4];
#pragma unroll
    for (int r = 0; r < 4; ++r) {
        hbT[r] = hb[m0 + quad * 4 + r];
        hbS[r] = hb[64 + m0 + quad * 4 + r];
    }
#pragma unroll
    for (int nt = 0; nt < 4; ++nt) {
#pragma unroll
        for (int r = 0; r < 4; ++r) {
            float xh = accT[nt][r] + hbT[r];
            float yh = accS[nt][r] + hbS[r];
            xh = fminf(fmaxf(xh, -15.f), 15.f);
            float e2 = __expf(2.f * xh);
            float th = (e2 - 1.f) / (e2 + 1.f);
            float sg = 1.f / (1.f + __expf(-yh));
            int o = m0 + quad * 4 + r;
            int t = nt * 16 + l15;
            Gt[t * 72 + o] = __float2bfloat16(th * sg);
        }
    }
    __syncthreads();

    // ---- GEMM2: R[16w..16w+15][64t] = Wres @ gated ----
    f32x4 accR[4];
#pragma unroll
    for (int nt = 0; nt < 4; ++nt) accR[nt] = zz;
    const __hip_bfloat16* wrA = wres + (size_t)(m0 + l15) * 64;
#pragma unroll
    for (int k0 = 0; k0 < 64; k0 += 32) {
        bf16x8 a = *(const bf16x8*)(wrA + k0 + quad * 8);
        int kk = k0 + quad * 8;
#pragma unroll
        for (int nt = 0; nt < 4; ++nt) {
            bf16x8 bx = *(const bf16x8*)(&Gt[(nt * 16 + l15) * 72 + kk]);
            accR[nt] = __builtin_amdgcn_mfma_f32_16x16x32_bf16(a, bx, accR[nt], 0, 0, 0);
        }
    }

    // ---- epilogue: next = R + rb + prev, one 8B store per (nt) ----
    float rbv[4];
#pragma unroll
    for (int r = 0; r < 4; ++r) rbv[r] = rb[m0 + quad * 4 + r];
#pragma unroll
    for (int nt = 0; nt < 4; ++nt) {
        int t = nt * 16 + l15;
        bf16x4 ov;
#pragma unroll
        for (int r = 0; r < 4; ++r) {
            int o = m0 + quad * 4 + r;
            float cur = __bfloat162float(Xc[t * 72 + o]);
            __hip_bfloat16 h = __float2bfloat16(accR[nt][r] + rbv[r] + cur);
            ov[r] = *(short*)&h;
        }
        *(bf16x4*)(nb + t * NCH + m0 + quad * 4) = ov;
    }

    // ---- fused skip->mix: acc[b][t] += sum_c mw[c]*gated[c][t] ----
    int tt  = tid & 63;
    int grp = tid >> 6;
    float s = 0.f;
#pragma unroll
    for (int c = 0; c < 16; ++c) {
        s += mw[grp * 16 + c] * __bfloat162float(Gt[tt * 72 + grp * 16 + c]);
    }
    skb[grp * 64 + tt] = s;
    __syncthreads();
    if (tid < 64) {
        float tot = skb[tid] + skb[64 + tid] + skb[128 + tid] + skb[192 + tid];
        acc[(size_t)b * T_LEN + t0 + tid] += tot;
    }
}

// ---------------------------------------------------------------------------
__global__ void finalize_kernel(const float* __restrict__ acc,
                                const float* __restrict__ mix_b,
                                float* __restrict__ out) {
    int gid = blockIdx.x * 256 + threadIdx.x;     // over B*T = 262144
    out[gid] = acc[gid] + mix_b[0];
}

// ---------------------------------------------------------------------------
extern "C" void kernel_launch(void* const* d_in, const int* in_sizes, int n_in,
                              void* d_out, int out_size, void* d_ws, size_t ws_size,
                              hipStream_t stream) {
    const float* x     = (const float*)d_in[0];
    const float* in_w  = (const float*)d_in[1];
    const float* in_b  = (const float*)d_in[2];
    const float* hid_w = (const float*)d_in[3];  // [18][128][64][2]
    const float* hid_b = (const float*)d_in[4];  // [18][128]
    const float* res_w = (const float*)d_in[5];  // [18][64][64][1]
    const float* res_b = (const float*)d_in[6];  // [18][64]
    const float* mix_w = (const float*)d_in[7];  // [1152]
    const float* mix_b = (const float*)d_in[8];  // [1]
    float* out = (float*)d_out;

    // ws layout (bytes): actA 32M | actB 32M | acc 1M | whid 0.56M | wres 0.14M
    const size_t act_elems = 4ull * T_LEN * NCH;     // 16M bf16 = 32 MB
    __hip_bfloat16* actA = (__hip_bfloat16*)d_ws;
    __hip_bfloat16* actB = actA + act_elems;
    float* acc = (float*)(actB + act_elems);         // [B][T] = 1 MB
    __hip_bfloat16* whid = (__hip_bfloat16*)(acc + 4ull * T_LEN);
    __hip_bfloat16* wres = whid + (size_t)NLAYER * 128 * 128;

    hipMemsetAsync(acc, 0, 4ull * T_LEN * sizeof(float), stream);

    convert_weights_kernel<<<1152, 256, 0, stream>>>(hid_w, res_w, whid, wres);

    input_conv_kernel<<<8192, 256, 0, stream>>>(x, in_w, in_b, actA);

    static const int dil[NLAYER] = {1, 2, 4, 8, 16, 32, 64, 128, 256,
                                    1, 2, 4, 8, 16, 32, 64, 128, 256};
    const __hip_bfloat16* cur = actA;
    __hip_bfloat16* nxt = actB;
    for (int i = 0; i < NLAYER; ++i) {
        layer_mfma_kernel<<<4 * 1024, 256, 0, stream>>>(
            cur, nxt, acc,
            whid + (size_t)i * 128 * 128,
            hid_b + (size_t)i * 128,
            wres + (size_t)i * 64 * 64,
            res_b + (size_t)i * 64,
            mix_w + (size_t)i * 64,
            dil[i]);
        const __hip_bfloat16* tmp = nxt;
        nxt = (__hip_bfloat16*)cur;
        cur = tmp;
    }

    finalize_kernel<<<1024, 256, 0, stream>>>(acc, mix_b, out);
}

// Round 4
// 592.873 us; speedup vs baseline: 10.9259x; 1.2862x over previous
//
#include <hip/hip_runtime.h>
#include <hip/hip_bf16.h>
#include <math.h>

#define NCH 64       // C
#define T_LEN 65536
#define NLAYER 18

typedef __attribute__((ext_vector_type(8))) short bf16x8;   // 8 bf16 = 4 VGPRs
typedef __attribute__((ext_vector_type(4))) short bf16x4;   // 4 bf16 = 2 VGPRs
typedef __attribute__((ext_vector_type(4))) float f32x4;

static __device__ __forceinline__ float bf2f(short s) {
    union { short u[2]; float f; } v;
    v.u[0] = 0; v.u[1] = s;
    return v.f;
}

// ---------------------------------------------------------------------------
// Input 1x1 conv -> bf16 [B][T][C] layout (channel-innermost).
// ---------------------------------------------------------------------------
__global__ void input_conv_kernel(const float* __restrict__ x,
                                  const float* __restrict__ in_w,
                                  const float* __restrict__ in_b,
                                  __hip_bfloat16* __restrict__ out) {
    int gid = blockIdx.x * 256 + threadIdx.x;     // over B*T*8 = 2M
    int c8 = gid & 7;
    int t  = (gid >> 3) & (T_LEN - 1);
    int b  = gid >> 19;
    float xv = x[(size_t)b * T_LEN + t];
    bf16x8 v;
#pragma unroll
    for (int j = 0; j < 8; ++j) {
        float o = in_w[c8 * 8 + j] * xv + in_b[c8 * 8 + j];
        __hip_bfloat16 h = __float2bfloat16(o);
        v[j] = *(short*)&h;
    }
    *(bf16x8*)(out + ((size_t)b * T_LEN + t) * NCH + c8 * 8) = v;
}

// ---------------------------------------------------------------------------
// whid[l][o][k]: k<64 -> hid_w[l][o][k][0] (past tap), k>=64 -> [k-64][1] (cur)
// ---------------------------------------------------------------------------
__global__ void convert_weights_kernel(const float* __restrict__ hid_w,
                                       const float* __restrict__ res_w,
                                       __hip_bfloat16* __restrict__ whid,
                                       __hip_bfloat16* __restrict__ wres) {
    int gid = blockIdx.x * 256 + threadIdx.x;
    if (gid < NLAYER * 128 * 128) {
        int l   = gid >> 14;
        int rem = gid & 16383;
        int o   = rem >> 7;
        int k   = rem & 127;
        float v = (k < 64)
            ? hid_w[((l * 128 + o) * 64 + k) * 2]
            : hid_w[((l * 128 + o) * 64 + (k - 64)) * 2 + 1];
        whid[gid] = __float2bfloat16(v);
    }
    if (gid < NLAYER * 64 * 64) {
        wres[gid] = __float2bfloat16(res_w[gid]);
    }
}

// ---------------------------------------------------------------------------
// One gated residual layer. Block = 256 thr (4 waves) owns t0..t0+63 and
// loops over all 4 batches (software-pipelined: batch b+1's global loads are
// in flight during batch b's compute; weights live in registers the whole
// kernel). 2 barriers/iter, single-buffered LDS (race-audited: all Xc/Xp
// reads happen before barrier B, all Gt reads before next iter's barrier A;
// stage-writes happen after barrier B, gate-writes after barrier A).
// ---------------------------------------------------------------------------
__global__ __launch_bounds__(256, 2) void layer_mfma_kernel(
    const __hip_bfloat16* __restrict__ prev,   // [B][T][C] bf16
    __hip_bfloat16* __restrict__ next,         // [B][T][C] bf16
    float* __restrict__ acc,                   // [B][T] fp32 skip accumulator
    const __hip_bfloat16* __restrict__ whid,   // [128][128] this layer
    const float* __restrict__ hb,              // [128]
    const __hip_bfloat16* __restrict__ wres,   // [64][64]
    const float* __restrict__ rb,              // [64]
    const float* __restrict__ mw,              // [64] this layer's mix slice
    int d) {
    __shared__ __align__(16) __hip_bfloat16 Xp[64 * 72];  // past tap [t][c]
    __shared__ __align__(16) __hip_bfloat16 Xc[64 * 72];  // cur  tap [t][c]
    __shared__ __align__(16) __hip_bfloat16 Gt[64 * 72];  // gated    [t][c]

    const int t0   = blockIdx.x << 6;          // grid = 1024 = T/64
    const int tid  = threadIdx.x;
    const int lane = tid & 63;
    const int w4   = tid >> 6;                 // wave id 0..3
    const int l15  = lane & 15;
    const int quad = lane >> 4;
    const int m0   = w4 * 16;

    const int rr = tid >> 3;                   // staging row 0..31
    const int co = (tid & 7) * 8;              // staging channel group

    // ---- hoist weights & biases into registers (reused for all 4 batches) ----
    bf16x8 aT[4], aS[4], aR[2];
    {
        const __hip_bfloat16* whT = whid + (size_t)(m0 + l15) * 128 + quad * 8;
        const __hip_bfloat16* whS = whT + 64 * 128;
#pragma unroll
        for (int k = 0; k < 4; ++k) {
            aT[k] = *(const bf16x8*)(whT + k * 32);
            aS[k] = *(const bf16x8*)(whS + k * 32);
        }
        const __hip_bfloat16* wrA = wres + (size_t)(m0 + l15) * 64 + quad * 8;
        aR[0] = *(const bf16x8*)(wrA);
        aR[1] = *(const bf16x8*)(wrA + 32);
    }
    f32x4 biasT, biasS, biasR;
#pragma unroll
    for (int r = 0; r < 4; ++r) {
        biasT[r] = hb[m0 + quad * 4 + r];
        biasS[r] = hb[64 + m0 + quad * 4 + r];
        biasR[r] = rb[m0 + quad * 4 + r];
    }
    float mwq[16];
#pragma unroll
    for (int j = 0; j < 16; ++j) mwq[j] = mw[quad * 16 + j];

    // ---- staging loads (to registers) ----
    bf16x8 pc[2], pp[2];
#define LOAD_TILE(b)                                                          \
    do {                                                                      \
        const __hip_bfloat16* pb = prev + ((size_t)(b) * T_LEN + t0) * NCH;   \
        _Pragma("unroll")                                                     \
        for (int pass = 0; pass < 2; ++pass) {                                \
            int r = pass * 32 + rr;                                           \
            pc[pass] = *(const bf16x8*)(pb + r * NCH + co);                   \
            int tp = t0 + r - d;                                              \
            bf16x8 z = {0, 0, 0, 0, 0, 0, 0, 0};                              \
            pp[pass] = z;                                                     \
            if (tp >= 0)                                                      \
                pp[pass] = *(const bf16x8*)(prev +                            \
                    ((size_t)(b) * T_LEN + tp) * NCH + co);                   \
        }                                                                     \
    } while (0)

    LOAD_TILE(0);

#pragma unroll
    for (int b = 0; b < 4; ++b) {
        // ---- drain staged regs into LDS ----
#pragma unroll
        for (int pass = 0; pass < 2; ++pass) {
            int r = pass * 32 + rr;
            *(bf16x8*)(&Xc[r * 72 + co]) = pc[pass];
            *(bf16x8*)(&Xp[r * 72 + co]) = pp[pass];
        }
        __syncthreads();                       // barrier A

        // ---- prefetch next batch (in flight during compute) ----
        if (b < 3) LOAD_TILE(b + 1);

        // ---- GEMM1: H[128][64] = Whid @ [past;cur], bias in acc init ----
        f32x4 accT[4], accS[4];
#pragma unroll
        for (int nt = 0; nt < 4; ++nt) { accT[nt] = biasT; accS[nt] = biasS; }
#pragma unroll
        for (int ks = 0; ks < 4; ++ks) {
            const __hip_bfloat16* src = (ks < 2) ? Xp : Xc;
            const int kk = (ks & 1) * 32 + quad * 8;
#pragma unroll
            for (int nt = 0; nt < 4; ++nt) {
                bf16x8 bx = *(const bf16x8*)(&src[(nt * 16 + l15) * 72 + kk]);
                accT[nt] = __builtin_amdgcn_mfma_f32_16x16x32_bf16(aT[ks], bx, accT[nt], 0, 0, 0);
                accS[nt] = __builtin_amdgcn_mfma_f32_16x16x32_bf16(aS[ks], bx, accS[nt], 0, 0, 0);
            }
        }

        // ---- gate -> Gt[t][c] (inf saturates correctly, no clamps) ----
#pragma unroll
        for (int nt = 0; nt < 4; ++nt) {
            int t = nt * 16 + l15;
#pragma unroll
            for (int r = 0; r < 4; ++r) {
                float e2 = __expf(2.f * accT[nt][r]);
                float th = 1.f - 2.f * __builtin_amdgcn_rcpf(e2 + 1.f);
                float sg = __builtin_amdgcn_rcpf(1.f + __expf(-accS[nt][r]));
                Gt[t * 72 + m0 + quad * 4 + r] = __float2bfloat16(th * sg);
            }
        }

        // ---- residual source -> regs (must precede barrier B) ----
        bf16x4 curres[4];
#pragma unroll
        for (int nt = 0; nt < 4; ++nt) {
            curres[nt] = *(const bf16x4*)(&Xc[(nt * 16 + l15) * 72 + m0 + quad * 4]);
        }
        __syncthreads();                       // barrier B

        // ---- GEMM2: R[64][64] = Wres @ gated, bias in acc init ----
        f32x4 accR[4];
#pragma unroll
        for (int nt = 0; nt < 4; ++nt) accR[nt] = biasR;
#pragma unroll
        for (int ks = 0; ks < 2; ++ks) {
            const int kk = ks * 32 + quad * 8;
#pragma unroll
            for (int nt = 0; nt < 4; ++nt) {
                bf16x8 bx = *(const bf16x8*)(&Gt[(nt * 16 + l15) * 72 + kk]);
                accR[nt] = __builtin_amdgcn_mfma_f32_16x16x32_bf16(aR[ks], bx, accR[nt], 0, 0, 0);
            }
        }

        // ---- epilogue: next = R + cur ----
        __hip_bfloat16* nb = next + ((size_t)b * T_LEN + t0) * NCH;
#pragma unroll
        for (int nt = 0; nt < 4; ++nt) {
            int t = nt * 16 + l15;
            bf16x4 ov;
#pragma unroll
            for (int r = 0; r < 4; ++r) {
                __hip_bfloat16 h = __float2bfloat16(accR[nt][r] + bf2f(curres[nt][r]));
                ov[r] = *(short*)&h;
            }
            *(bf16x4*)(nb + t * NCH + m0 + quad * 4) = ov;
        }

        // ---- fused skip->mix: wave-local shuffle reduction ----
        {
            int t = w4 * 16 + l15;
            bf16x8 g0 = *(const bf16x8*)(&Gt[t * 72 + quad * 16]);
            bf16x8 g1 = *(const bf16x8*)(&Gt[t * 72 + quad * 16 + 8]);
            float s = 0.f;
#pragma unroll
            for (int j = 0; j < 8; ++j) {
                s += mwq[j]     * bf2f(g0[j]);
                s += mwq[8 + j] * bf2f(g1[j]);
            }
            s += __shfl_xor(s, 16, 64);
            s += __shfl_xor(s, 32, 64);
            if (quad == 0)
                acc[(size_t)b * T_LEN + t0 + t] += s;
        }
    }
#undef LOAD_TILE
}

// ---------------------------------------------------------------------------
__global__ void finalize_kernel(const float* __restrict__ acc,
                                const float* __restrict__ mix_b,
                                float* __restrict__ out) {
    int gid = blockIdx.x * 256 + threadIdx.x;     // over B*T = 262144
    out[gid] = acc[gid] + mix_b[0];
}

// ---------------------------------------------------------------------------
extern "C" void kernel_launch(void* const* d_in, const int* in_sizes, int n_in,
                              void* d_out, int out_size, void* d_ws, size_t ws_size,
                              hipStream_t stream) {
    const float* x     = (const float*)d_in[0];
    const float* in_w  = (const float*)d_in[1];
    const float* in_b  = (const float*)d_in[2];
    const float* hid_w = (const float*)d_in[3];  // [18][128][64][2]
    const float* hid_b = (const float*)d_in[4];  // [18][128]
    const float* res_w = (const float*)d_in[5];  // [18][64][64][1]
    const float* res_b = (const float*)d_in[6];  // [18][64]
    const float* mix_w = (const float*)d_in[7];  // [1152]
    const float* mix_b = (const float*)d_in[8];  // [1]
    float* out = (float*)d_out;

    // ws layout: actA 32M | actB 32M | acc 1M | whid 0.56M | wres 0.14M
    const size_t act_elems = 4ull * T_LEN * NCH;     // 16M bf16 = 32 MB
    __hip_bfloat16* actA = (__hip_bfloat16*)d_ws;
    __hip_bfloat16* actB = actA + act_elems;
    float* acc = (float*)(actB + act_elems);         // [B][T] = 1 MB
    __hip_bfloat16* whid = (__hip_bfloat16*)(acc + 4ull * T_LEN);
    __hip_bfloat16* wres = whid + (size_t)NLAYER * 128 * 128;

    hipMemsetAsync(acc, 0, 4ull * T_LEN * sizeof(float), stream);

    convert_weights_kernel<<<1152, 256, 0, stream>>>(hid_w, res_w, whid, wres);

    input_conv_kernel<<<8192, 256, 0, stream>>>(x, in_w, in_b, actA);

    static const int dil[NLAYER] = {1, 2, 4, 8, 16, 32, 64, 128, 256,
                                    1, 2, 4, 8, 16, 32, 64, 128, 256};
    const __hip_bfloat16* cur = actA;
    __hip_bfloat16* nxt = actB;
    for (int i = 0; i < NLAYER; ++i) {
        layer_mfma_kernel<<<1024, 256, 0, stream>>>(
            cur, nxt, acc,
            whid + (size_t)i * 128 * 128,
            hid_b + (size_t)i * 128,
            wres + (size_t)i * 64 * 64,
            res_b + (size_t)i * 64,
            mix_w + (size_t)i * 64,
            dil[i]);
        const __hip_bfloat16* tmp = nxt;
        nxt = (__hip_bfloat16*)cur;
        cur = tmp;
    }

    finalize_kernel<<<1024, 256, 0, stream>>>(acc, mix_b, out);
}

// Round 5
// 555.992 us; speedup vs baseline: 11.6506x; 1.0663x over previous
//
#include <hip/hip_runtime.h>
#include <hip/hip_bf16.h>
#include <math.h>

#define NCH 64       // C
#define T_LEN 65536
#define NLAYER 18

typedef __attribute__((ext_vector_type(8))) short bf16x8;   // 8 bf16 = 4 VGPRs
typedef __attribute__((ext_vector_type(4))) short bf16x4;   // 4 bf16 = 2 VGPRs
typedef __attribute__((ext_vector_type(4))) float f32x4;

static __device__ __forceinline__ float bf2f(short s) {
    union { short u[2]; float f; } v;
    v.u[0] = 0; v.u[1] = s;
    return v.f;
}
static __device__ __forceinline__ short f2bf(float f) {
    __hip_bfloat16 h = __float2bfloat16(f);
    return *(short*)&h;
}

// ---------------------------------------------------------------------------
// whid[l][o][k]: k<64 -> hid_w[l][o][k][0] (past tap), k>=64 -> [k-64][1] (cur)
// ---------------------------------------------------------------------------
__global__ void convert_weights_kernel(const float* __restrict__ hid_w,
                                       const float* __restrict__ res_w,
                                       __hip_bfloat16* __restrict__ whid,
                                       __hip_bfloat16* __restrict__ wres) {
    int gid = blockIdx.x * 256 + threadIdx.x;
    if (gid < NLAYER * 128 * 128) {
        int l   = gid >> 14;
        int rem = gid & 16383;
        int o   = rem >> 7;
        int k   = rem & 127;
        float v = (k < 64)
            ? hid_w[((l * 128 + o) * 64 + k) * 2]
            : hid_w[((l * 128 + o) * 64 + (k - 64)) * 2 + 1];
        whid[gid] = __float2bfloat16(v);
    }
    if (gid < NLAYER * 64 * 64) {
        wres[gid] = __float2bfloat16(res_w[gid]);
    }
}

// ---------------------------------------------------------------------------
// Fused 6-layer pass (dilations 1,2,4,8,16,32; halo sum = 63 < 64).
// Block = 256 thr owns window [t0-64, t0+128): 64-halo + 128 output.
// A[192][72] holds the residual stream in-place across layers (validity edge
// moves right by d per layer; outputs [t0, t0+128) stay valid). G holds the
// gated activations of the current layer. Weights reload per layer (L2-hot).
// Skip->mix accumulated in registers across all 6 layers, one acc RMW.
// is_first: staging computes the input 1x1 conv from x directly.
// Causal edge: rows with global t<0 are zeroed at staging AND after every
// layer epilogue (reference zero-pads each conv input).
// ---------------------------------------------------------------------------
__global__ __launch_bounds__(256, 2) void fused6_kernel(
    const void* __restrict__ src,                 // fp32 x | bf16 prev
    __hip_bfloat16* __restrict__ next,            // [B][T][C]
    float* __restrict__ acc,                      // [B][T]
    const __hip_bfloat16* __restrict__ whid_all,  // [18][128][128]
    const float* __restrict__ hb_all,             // [18][128]
    const __hip_bfloat16* __restrict__ wres_all,  // [18][64][64]
    const float* __restrict__ rb_all,             // [18][64]
    const float* __restrict__ mix_w,              // [1152]
    const float* __restrict__ in_w,               // [64]
    const float* __restrict__ in_b,               // [64]
    int lbase, int is_first) {
    __shared__ __align__(16) __hip_bfloat16 A[192 * 72];
    __shared__ __align__(16) __hip_bfloat16 G[192 * 72];

    const int b    = blockIdx.x >> 9;          // 512 windows per batch
    const int widx = blockIdx.x & 511;
    const int t0   = widx << 7;
    const int tw   = t0 - 64;

    const int tid  = threadIdx.x;
    const int lane = tid & 63;
    const int w4   = tid >> 6;
    const int l15  = lane & 15;
    const int quad = lane >> 4;
    const int m0   = w4 * 16;
    const int rr   = tid >> 3;                 // 0..31
    const int co   = (tid & 7) * 8;

    // ---- stage input window [tw, tw+192) ----
    if (is_first) {
        const float* x = (const float*)src;
        float iw[8], ib[8];
#pragma unroll
        for (int j = 0; j < 8; ++j) { iw[j] = in_w[co + j]; ib[j] = in_b[co + j]; }
#pragma unroll
        for (int round = 0; round < 6; ++round) {
            int r  = round * 32 + rr;
            int gt = tw + r;
            bf16x8 v = {0, 0, 0, 0, 0, 0, 0, 0};
            if (gt >= 0) {
                float xv = x[(size_t)b * T_LEN + gt];
#pragma unroll
                for (int j = 0; j < 8; ++j) v[j] = f2bf(iw[j] * xv + ib[j]);
            }
            *(bf16x8*)(&A[r * 72 + co]) = v;
        }
    } else {
        const __hip_bfloat16* prev = (const __hip_bfloat16*)src;
#pragma unroll
        for (int round = 0; round < 6; ++round) {
            int r  = round * 32 + rr;
            int gt = tw + r;
            bf16x8 v = {0, 0, 0, 0, 0, 0, 0, 0};
            if (gt >= 0)
                v = *(const bf16x8*)(prev + ((size_t)b * T_LEN + gt) * NCH + co);
            *(bf16x8*)(&A[r * 72 + co]) = v;
        }
    }

    float skacc0 = 0.f, skacc1 = 0.f;

#pragma unroll 1
    for (int l = 0; l < 6; ++l) {
        const int d = 1 << l;
        const __hip_bfloat16* whid = whid_all + (size_t)(lbase + l) * 16384;
        const __hip_bfloat16* wres = wres_all + (size_t)(lbase + l) * 4096;
        const float* hb = hb_all + (lbase + l) * 128;
        const float* rb = rb_all + (lbase + l) * 64;
        const float* mw = mix_w + (lbase + l) * 64;

        // ---- per-layer weights to registers ----
        bf16x8 aT[4], aS[4], aR[2];
        {
            const __hip_bfloat16* whT = whid + (size_t)(m0 + l15) * 128 + quad * 8;
            const __hip_bfloat16* whS = whT + 64 * 128;
#pragma unroll
            for (int k = 0; k < 4; ++k) {
                aT[k] = *(const bf16x8*)(whT + k * 32);
                aS[k] = *(const bf16x8*)(whS + k * 32);
            }
            const __hip_bfloat16* wrA = wres + (size_t)(m0 + l15) * 64 + quad * 8;
            aR[0] = *(const bf16x8*)(wrA);
            aR[1] = *(const bf16x8*)(wrA + 32);
        }
        f32x4 biasT, biasS, biasR;
#pragma unroll
        for (int r = 0; r < 4; ++r) {
            biasT[r] = hb[m0 + quad * 4 + r];
            biasS[r] = hb[64 + m0 + quad * 4 + r];
            biasR[r] = rb[m0 + quad * 4 + r];
        }
        float mwq[16];
#pragma unroll
        for (int k = 0; k < 4; ++k) {
            float4 m4 = *(const float4*)(mw + quad * 16 + k * 4);
            mwq[k * 4 + 0] = m4.x; mwq[k * 4 + 1] = m4.y;
            mwq[k * 4 + 2] = m4.z; mwq[k * 4 + 3] = m4.w;
        }

        __syncthreads();   // staging / previous epilogue A-writes visible

        // ---- phase 1: GEMM1 + gate, all 3 chunks of 64 t ----
#pragma unroll
        for (int ct = 0; ct < 3; ++ct) {
            f32x4 accT[4], accS[4];
#pragma unroll
            for (int nt = 0; nt < 4; ++nt) { accT[nt] = biasT; accS[nt] = biasS; }
#pragma unroll
            for (int ks = 0; ks < 4; ++ks) {
                const int koff = (ks & 1) * 32 + quad * 8;
#pragma unroll
                for (int nt = 0; nt < 4; ++nt) {
                    int trow = ct * 64 + nt * 16 + l15;
                    int prow = trow - d;  prow = prow < 0 ? 0 : prow;
                    int row  = (ks < 2) ? prow : trow;
                    bf16x8 bx = *(const bf16x8*)(&A[row * 72 + koff]);
                    accT[nt] = __builtin_amdgcn_mfma_f32_16x16x32_bf16(aT[ks], bx, accT[nt], 0, 0, 0);
                    accS[nt] = __builtin_amdgcn_mfma_f32_16x16x32_bf16(aS[ks], bx, accS[nt], 0, 0, 0);
                }
            }
#pragma unroll
            for (int nt = 0; nt < 4; ++nt) {
                int trow = ct * 64 + nt * 16 + l15;
                bf16x4 gv;
#pragma unroll
                for (int r = 0; r < 4; ++r) {
                    float e2 = __expf(2.f * accT[nt][r]);
                    float th = 1.f - 2.f * __builtin_amdgcn_rcpf(e2 + 1.f);
                    float sg = __builtin_amdgcn_rcpf(1.f + __expf(-accS[nt][r]));
                    gv[r] = f2bf(th * sg);
                }
                *(bf16x4*)(&G[trow * 72 + m0 + quad * 4]) = gv;
            }
        }
        __syncthreads();  // G complete, all A-reads of GEMM1 done

        // ---- phase 2: GEMM2 + in-place residual epilogue ----
#pragma unroll
        for (int ct = 0; ct < 3; ++ct) {
            f32x4 accR[4];
#pragma unroll
            for (int nt = 0; nt < 4; ++nt) accR[nt] = biasR;
#pragma unroll
            for (int ks = 0; ks < 2; ++ks) {
                const int koff = ks * 32 + quad * 8;
#pragma unroll
                for (int nt = 0; nt < 4; ++nt) {
                    int trow = ct * 64 + nt * 16 + l15;
                    bf16x8 bx = *(const bf16x8*)(&G[trow * 72 + koff]);
                    accR[nt] = __builtin_amdgcn_mfma_f32_16x16x32_bf16(aR[ks], bx, accR[nt], 0, 0, 0);
                }
            }
#pragma unroll
            for (int nt = 0; nt < 4; ++nt) {
                int trow = ct * 64 + nt * 16 + l15;
                bf16x4 old = *(const bf16x4*)(&A[trow * 72 + m0 + quad * 4]);
                bool ok = (tw + trow) >= 0;   // causal zero for global t<0
                bf16x4 ov;
#pragma unroll
                for (int r = 0; r < 4; ++r) {
                    float v = accR[nt][r] + bf2f(old[r]);
                    ov[r] = f2bf(ok ? v : 0.f);
                }
                *(bf16x4*)(&A[trow * 72 + m0 + quad * 4]) = ov;
            }
        }

        // ---- skip->mix partials over output region [64,192) ----
#pragma unroll
        for (int s = 0; s < 2; ++s) {
            int p = 64 + w4 * 32 + s * 16 + l15;
            bf16x8 g0 = *(const bf16x8*)(&G[p * 72 + quad * 16]);
            bf16x8 g1 = *(const bf16x8*)(&G[p * 72 + quad * 16 + 8]);
            float sv = 0.f;
#pragma unroll
            for (int j = 0; j < 8; ++j) {
                sv += mwq[j]     * bf2f(g0[j]);
                sv += mwq[8 + j] * bf2f(g1[j]);
            }
            if (s == 0) skacc0 += sv; else skacc1 += sv;
        }
    }
    __syncthreads();  // last epilogue visible

    // ---- write output window [t0, t0+128) ----
#pragma unroll
    for (int round = 0; round < 4; ++round) {
        int pr = round * 32 + rr;
        *(bf16x8*)(next + ((size_t)b * T_LEN + t0 + pr) * NCH + co) =
            *(const bf16x8*)(&A[(pr + 64) * 72 + co]);
    }

    // ---- skip accumulate (quad-reduce, exclusive t-ownership -> plain RMW) ----
    skacc0 += __shfl_xor(skacc0, 16, 64);
    skacc0 += __shfl_xor(skacc0, 32, 64);
    skacc1 += __shfl_xor(skacc1, 16, 64);
    skacc1 += __shfl_xor(skacc1, 32, 64);
    if (quad == 0) {
        acc[(size_t)b * T_LEN + t0 + w4 * 32 + l15]      += skacc0;
        acc[(size_t)b * T_LEN + t0 + w4 * 32 + 16 + l15] += skacc1;
    }
}

// ---------------------------------------------------------------------------
// Single-layer pass for d in {64,128} (and any standalone layer).
// Unchanged R4 structure: 4-batch loop, register prefetch, weights hoisted.
// ---------------------------------------------------------------------------
__global__ __launch_bounds__(256, 2) void layer_mfma_kernel(
    const __hip_bfloat16* __restrict__ prev,   // [B][T][C] bf16
    __hip_bfloat16* __restrict__ next,         // [B][T][C] bf16
    float* __restrict__ acc,                   // [B][T]
    const __hip_bfloat16* __restrict__ whid,   // [128][128] this layer
    const float* __restrict__ hb,              // [128]
    const __hip_bfloat16* __restrict__ wres,   // [64][64]
    const float* __restrict__ rb,              // [64]
    const float* __restrict__ mw,              // [64]
    int d) {
    __shared__ __align__(16) __hip_bfloat16 Xp[64 * 72];
    __shared__ __align__(16) __hip_bfloat16 Xc[64 * 72];
    __shared__ __align__(16) __hip_bfloat16 Gt[64 * 72];

    const int t0   = blockIdx.x << 6;
    const int tid  = threadIdx.x;
    const int lane = tid & 63;
    const int w4   = tid >> 6;
    const int l15  = lane & 15;
    const int quad = lane >> 4;
    const int m0   = w4 * 16;
    const int rr = tid >> 3;
    const int co = (tid & 7) * 8;

    bf16x8 aT[4], aS[4], aR[2];
    {
        const __hip_bfloat16* whT = whid + (size_t)(m0 + l15) * 128 + quad * 8;
        const __hip_bfloat16* whS = whT + 64 * 128;
#pragma unroll
        for (int k = 0; k < 4; ++k) {
            aT[k] = *(const bf16x8*)(whT + k * 32);
            aS[k] = *(const bf16x8*)(whS + k * 32);
        }
        const __hip_bfloat16* wrA = wres + (size_t)(m0 + l15) * 64 + quad * 8;
        aR[0] = *(const bf16x8*)(wrA);
        aR[1] = *(const bf16x8*)(wrA + 32);
    }
    f32x4 biasT, biasS, biasR;
#pragma unroll
    for (int r = 0; r < 4; ++r) {
        biasT[r] = hb[m0 + quad * 4 + r];
        biasS[r] = hb[64 + m0 + quad * 4 + r];
        biasR[r] = rb[m0 + quad * 4 + r];
    }
    float mwq[16];
#pragma unroll
    for (int j = 0; j < 16; ++j) mwq[j] = mw[quad * 16 + j];

    bf16x8 pc[2], pp[2];
#define LOAD_TILE(b)                                                          \
    do {                                                                      \
        const __hip_bfloat16* pb = prev + ((size_t)(b) * T_LEN + t0) * NCH;   \
        _Pragma("unroll")                                                     \
        for (int pass = 0; pass < 2; ++pass) {                                \
            int r = pass * 32 + rr;                                           \
            pc[pass] = *(const bf16x8*)(pb + r * NCH + co);                   \
            int tp = t0 + r - d;                                              \
            bf16x8 z = {0, 0, 0, 0, 0, 0, 0, 0};                              \
            pp[pass] = z;                                                     \
            if (tp >= 0)                                                      \
                pp[pass] = *(const bf16x8*)(prev +                            \
                    ((size_t)(b) * T_LEN + tp) * NCH + co);                   \
        }                                                                     \
    } while (0)

    LOAD_TILE(0);

#pragma unroll
    for (int b = 0; b < 4; ++b) {
#pragma unroll
        for (int pass = 0; pass < 2; ++pass) {
            int r = pass * 32 + rr;
            *(bf16x8*)(&Xc[r * 72 + co]) = pc[pass];
            *(bf16x8*)(&Xp[r * 72 + co]) = pp[pass];
        }
        __syncthreads();                       // barrier A

        if (b < 3) LOAD_TILE(b + 1);

        f32x4 accT[4], accS[4];
#pragma unroll
        for (int nt = 0; nt < 4; ++nt) { accT[nt] = biasT; accS[nt] = biasS; }
#pragma unroll
        for (int ks = 0; ks < 4; ++ks) {
            const __hip_bfloat16* srcb = (ks < 2) ? Xp : Xc;
            const int kk = (ks & 1) * 32 + quad * 8;
#pragma unroll
            for (int nt = 0; nt < 4; ++nt) {
                bf16x8 bx = *(const bf16x8*)(&srcb[(nt * 16 + l15) * 72 + kk]);
                accT[nt] = __builtin_amdgcn_mfma_f32_16x16x32_bf16(aT[ks], bx, accT[nt], 0, 0, 0);
                accS[nt] = __builtin_amdgcn_mfma_f32_16x16x32_bf16(aS[ks], bx, accS[nt], 0, 0, 0);
            }
        }

#pragma unroll
        for (int nt = 0; nt < 4; ++nt) {
            int t = nt * 16 + l15;
#pragma unroll
            for (int r = 0; r < 4; ++r) {
                float e2 = __expf(2.f * accT[nt][r]);
                float th = 1.f - 2.f * __builtin_amdgcn_rcpf(e2 + 1.f);
                float sg = __builtin_amdgcn_rcpf(1.f + __expf(-accS[nt][r]));
                Gt[t * 72 + m0 + quad * 4 + r] = __float2bfloat16(th * sg);
            }
        }

        bf16x4 curres[4];
#pragma unroll
        for (int nt = 0; nt < 4; ++nt) {
            curres[nt] = *(const bf16x4*)(&Xc[(nt * 16 + l15) * 72 + m0 + quad * 4]);
        }
        __syncthreads();                       // barrier B

        f32x4 accR[4];
#pragma unroll
        for (int nt = 0; nt < 4; ++nt) accR[nt] = biasR;
#pragma unroll
        for (int ks = 0; ks < 2; ++ks) {
            const int kk = ks * 32 + quad * 8;
#pragma unroll
            for (int nt = 0; nt < 4; ++nt) {
                bf16x8 bx = *(const bf16x8*)(&Gt[(nt * 16 + l15) * 72 + kk]);
                accR[nt] = __builtin_amdgcn_mfma_f32_16x16x32_bf16(aR[ks], bx, accR[nt], 0, 0, 0);
            }
        }

        __hip_bfloat16* nb = next + ((size_t)b * T_LEN + t0) * NCH;
#pragma unroll
        for (int nt = 0; nt < 4; ++nt) {
            int t = nt * 16 + l15;
            bf16x4 ov;
#pragma unroll
            for (int r = 0; r < 4; ++r) {
                ov[r] = f2bf(accR[nt][r] + bf2f(curres[nt][r]));
            }
            *(bf16x4*)(nb + t * NCH + m0 + quad * 4) = ov;
        }

        {
            int t = w4 * 16 + l15;
            bf16x8 g0 = *(const bf16x8*)(&Gt[t * 72 + quad * 16]);
            bf16x8 g1 = *(const bf16x8*)(&Gt[t * 72 + quad * 16 + 8]);
            float s = 0.f;
#pragma unroll
            for (int j = 0; j < 8; ++j) {
                s += mwq[j]     * bf2f(g0[j]);
                s += mwq[8 + j] * bf2f(g1[j]);
            }
            s += __shfl_xor(s, 16, 64);
            s += __shfl_xor(s, 32, 64);
            if (quad == 0)
                acc[(size_t)b * T_LEN + t0 + t] += s;
        }
    }
#undef LOAD_TILE
}

// ---------------------------------------------------------------------------
// Last layer (17, d=256): GEMM1 + gate + skip only (res-conv output unused),
// fused finalize: out = acc + own skip + mix_b. No next write.
// ---------------------------------------------------------------------------
__global__ __launch_bounds__(256, 2) void last_layer_kernel(
    const __hip_bfloat16* __restrict__ prev,   // [B][T][C]
    const float* __restrict__ acc,             // [B][T] (layers 0..16 summed)
    float* __restrict__ out,                   // [B][T] fp32
    const __hip_bfloat16* __restrict__ whid,   // [128][128] layer 17
    const float* __restrict__ hb,              // [128]
    const float* __restrict__ mw,              // [64] layer-17 mix slice
    const float* __restrict__ mix_b,           // [1]
    int d) {
    __shared__ __align__(16) __hip_bfloat16 Xp[64 * 72];
    __shared__ __align__(16) __hip_bfloat16 Xc[64 * 72];
    __shared__ float skb[4 * 64];

    const int t0   = blockIdx.x << 6;
    const int tid  = threadIdx.x;
    const int lane = tid & 63;
    const int w4   = tid >> 6;
    const int l15  = lane & 15;
    const int quad = lane >> 4;
    const int m0   = w4 * 16;
    const int rr = tid >> 3;
    const int co = (tid & 7) * 8;

    bf16x8 aT[4], aS[4];
    {
        const __hip_bfloat16* whT = whid + (size_t)(m0 + l15) * 128 + quad * 8;
        const __hip_bfloat16* whS = whT + 64 * 128;
#pragma unroll
        for (int k = 0; k < 4; ++k) {
            aT[k] = *(const bf16x8*)(whT + k * 32);
            aS[k] = *(const bf16x8*)(whS + k * 32);
        }
    }
    f32x4 biasT, biasS;
    float mwv[4];
#pragma unroll
    for (int r = 0; r < 4; ++r) {
        biasT[r] = hb[m0 + quad * 4 + r];
        biasS[r] = hb[64 + m0 + quad * 4 + r];
        mwv[r]   = mw[m0 + quad * 4 + r];
    }
    const float mb = mix_b[0];

    bf16x8 pc[2], pp[2];
#define LOAD_TILE(b)                                                          \
    do {                                                                      \
        const __hip_bfloat16* pb = prev + ((size_t)(b) * T_LEN + t0) * NCH;   \
        _Pragma("unroll")                                                     \
        for (int pass = 0; pass < 2; ++pass) {                                \
            int r = pass * 32 + rr;                                           \
            pc[pass] = *(const bf16x8*)(pb + r * NCH + co);                   \
            int tp = t0 + r - d;                                              \
            bf16x8 z = {0, 0, 0, 0, 0, 0, 0, 0};                              \
            pp[pass] = z;                                                     \
            if (tp >= 0)                                                      \
                pp[pass] = *(const bf16x8*)(prev +                            \
                    ((size_t)(b) * T_LEN + tp) * NCH + co);                   \
        }                                                                     \
    } while (0)

    LOAD_TILE(0);

#pragma unroll
    for (int b = 0; b < 4; ++b) {
#pragma unroll
        for (int pass = 0; pass < 2; ++pass) {
            int r = pass * 32 + rr;
            *(bf16x8*)(&Xc[r * 72 + co]) = pc[pass];
            *(bf16x8*)(&Xp[r * 72 + co]) = pp[pass];
        }
        __syncthreads();                       // barrier A

        if (b < 3) LOAD_TILE(b + 1);

        f32x4 accT[4], accS[4];
#pragma unroll
        for (int nt = 0; nt < 4; ++nt) { accT[nt] = biasT; accS[nt] = biasS; }
#pragma unroll
        for (int ks = 0; ks < 4; ++ks) {
            const __hip_bfloat16* srcb = (ks < 2) ? Xp : Xc;
            const int kk = (ks & 1) * 32 + quad * 8;
#pragma unroll
            for (int nt = 0; nt < 4; ++nt) {
                bf16x8 bx = *(const bf16x8*)(&srcb[(nt * 16 + l15) * 72 + kk]);
                accT[nt] = __builtin_amdgcn_mfma_f32_16x16x32_bf16(aT[ks], bx, accT[nt], 0, 0, 0);
                accS[nt] = __builtin_amdgcn_mfma_f32_16x16x32_bf16(aS[ks], bx, accS[nt], 0, 0, 0);
            }
        }

        // gate + skip partial (no Gt/GEMM2 needed for last layer)
#pragma unroll
        for (int nt = 0; nt < 4; ++nt) {
            float sv = 0.f;
#pragma unroll
            for (int r = 0; r < 4; ++r) {
                float e2 = __expf(2.f * accT[nt][r]);
                float th = 1.f - 2.f * __builtin_amdgcn_rcpf(e2 + 1.f);
                float sg = __builtin_amdgcn_rcpf(1.f + __expf(-accS[nt][r]));
                sv += mwv[r] * (th * sg);
            }
            sv += __shfl_xor(sv, 16, 64);
            sv += __shfl_xor(sv, 32, 64);
            if (quad == 0)
                skb[w4 * 64 + nt * 16 + l15] = sv;
        }
        __syncthreads();                       // barrier B

        if (tid < 64) {
            float tot = skb[tid] + skb[64 + tid] + skb[128 + tid] + skb[192 + tid];
            out[(size_t)b * T_LEN + t0 + tid] =
                acc[(size_t)b * T_LEN + t0 + tid] + tot + mb;
        }
    }
#undef LOAD_TILE
}

// ---------------------------------------------------------------------------
extern "C" void kernel_launch(void* const* d_in, const int* in_sizes, int n_in,
                              void* d_out, int out_size, void* d_ws, size_t ws_size,
                              hipStream_t stream) {
    const float* x     = (const float*)d_in[0];
    const float* in_w  = (const float*)d_in[1];
    const float* in_b  = (const float*)d_in[2];
    const float* hid_w = (const float*)d_in[3];  // [18][128][64][2]
    const float* hid_b = (const float*)d_in[4];  // [18][128]
    const float* res_w = (const float*)d_in[5];  // [18][64][64][1]
    const float* res_b = (const float*)d_in[6];  // [18][64]
    const float* mix_w = (const float*)d_in[7];  // [1152]
    const float* mix_b = (const float*)d_in[8];  // [1]
    float* out = (float*)d_out;

    // ws layout: actA 32M | actB 32M | acc 1M | whid 0.56M | wres 0.14M
    const size_t act_elems = 4ull * T_LEN * NCH;     // 16M bf16 = 32 MB
    __hip_bfloat16* actA = (__hip_bfloat16*)d_ws;
    __hip_bfloat16* actB = actA + act_elems;
    float* acc = (float*)(actB + act_elems);         // [B][T] = 1 MB
    __hip_bfloat16* whid = (__hip_bfloat16*)(acc + 4ull * T_LEN);
    __hip_bfloat16* wres = whid + (size_t)NLAYER * 128 * 128;

    hipMemsetAsync(acc, 0, 4ull * T_LEN * sizeof(float), stream);

    convert_weights_kernel<<<1152, 256, 0, stream>>>(hid_w, res_w, whid, wres);

    // P0: input conv + layers 0-5 (d=1..32) fused -> actA
    fused6_kernel<<<2048, 256, 0, stream>>>(
        x, actA, acc, whid, hid_b, wres, res_b, mix_w, in_w, in_b, 0, 1);

    // P1-P3: layers 6,7,8 (d=64,128,256)
    layer_mfma_kernel<<<1024, 256, 0, stream>>>(
        actA, actB, acc, whid + 6 * 16384, hid_b + 6 * 128,
        wres + 6 * 4096, res_b + 6 * 64, mix_w + 6 * 64, 64);
    layer_mfma_kernel<<<1024, 256, 0, stream>>>(
        actB, actA, acc, whid + 7 * 16384, hid_b + 7 * 128,
        wres + 7 * 4096, res_b + 7 * 64, mix_w + 7 * 64, 128);
    layer_mfma_kernel<<<1024, 256, 0, stream>>>(
        actA, actB, acc, whid + 8 * 16384, hid_b + 8 * 128,
        wres + 8 * 4096, res_b + 8 * 64, mix_w + 8 * 64, 256);

    // P4: layers 9-14 (d=1..32) fused -> actA
    fused6_kernel<<<2048, 256, 0, stream>>>(
        actB, actA, acc, whid, hid_b, wres, res_b, mix_w, in_w, in_b, 9, 0);

    // P5-P6: layers 15,16 (d=64,128)
    layer_mfma_kernel<<<1024, 256, 0, stream>>>(
        actA, actB, acc, whid + 15 * 16384, hid_b + 15 * 128,
        wres + 15 * 4096, res_b + 15 * 64, mix_w + 15 * 64, 64);
    layer_mfma_kernel<<<1024, 256, 0, stream>>>(
        actB, actA, acc, whid + 16 * 16384, hid_b + 16 * 128,
        wres + 16 * 4096, res_b + 16 * 64, mix_w + 16 * 64, 128);

    // P7: layer 17 (d=256) + finalize -> out
    last_layer_kernel<<<1024, 256, 0, stream>>>(
        actA, acc, out, whid + 17 * 16384, hid_b + 17 * 128,
        mix_w + 17 * 64, mix_b, 256);
}